// Round 3
// baseline (128.630 us; speedup 1.0000x reference)
//
#include <hip/hip_runtime.h>
#include <math.h>

#define NG 2048
#define FEATN 128
#define NCHUNK 8
#define CHSZ 256
#define LOG2E 1.4426950408889634f

// ws float-offsets
// RAW params: 11 arrays of NG: u,v,a2,b2,c2,op,r,g,bl,rx,ry
#define P_U   0
#define P_V   1
#define P_A   2
#define P_B   3
#define P_C   4
#define P_OP  5
#define P_R   6
#define P_G   7
#define P_BL  8
#define P_RX  9
#define P_RY  10
#define KEY_OFF  (12 * NG)   // u64[NG]
#define SORT_OFF (16 * NG)   // 11 arrays of NG, depth-sorted

__device__ __forceinline__ float sigmoidf_(float z) { return 1.0f / (1.0f + expf(-z)); }

__global__ __launch_bounds__(64) void k_pre(
    const float* __restrict__ x, const float* __restrict__ pts, const float* __restrict__ vm,
    const float* __restrict__ w_shs, const float* __restrict__ b_shs,
    const float* __restrict__ w_scale, const float* __restrict__ b_scale,
    const float* __restrict__ w_xyz, const float* __restrict__ b_xyz,
    const float* __restrict__ w_opac, const float* __restrict__ b_opac,
    const float* __restrict__ w_rot, const float* __restrict__ b_rot,
    float* __restrict__ ws)
{
    __shared__ float sw[14 * FEATN];
    int tid = threadIdx.x;
    for (int i = tid; i < 14 * FEATN; i += 64) {
        int r = i >> 7, c0 = i & 127;
        float v;
        if (r < 3)       v = w_shs[r * FEATN + c0];
        else if (r < 6)  v = w_scale[(r - 3) * FEATN + c0];
        else if (r < 9)  v = w_xyz[(r - 6) * FEATN + c0];
        else if (r == 9) v = w_opac[c0];
        else             v = w_rot[(r - 10) * FEATN + c0];
        sw[i] = v;
    }
    __syncthreads();
    int g = blockIdx.x * 64 + tid;

    float acc[14];
#pragma unroll
    for (int j = 0; j < 14; j++) acc[j] = 0.0f;
    const float4* x4 = (const float4*)(x + (size_t)g * FEATN);
#pragma unroll 4
    for (int k4 = 0; k4 < FEATN / 4; k4++) {
        float4 xv = x4[k4];
#pragma unroll
        for (int j = 0; j < 14; j++) {
            const float* wr = &sw[j * FEATN + k4 * 4];
            acc[j] += xv.x * wr[0] + xv.y * wr[1] + xv.z * wr[2] + xv.w * wr[3];
        }
    }

    float r0 = sigmoidf_(acc[0] + b_shs[0]);
    float r1 = sigmoidf_(acc[1] + b_shs[1]);
    float r2 = sigmoidf_(acc[2] + b_shs[2]);
    float s0 = fminf(expf(acc[3] + b_scale[0]), 0.2f);
    float s1 = fminf(expf(acc[4] + b_scale[1]), 0.2f);
    float s2 = fminf(expf(acc[5] + b_scale[2]), 0.2f);
    float o0 = (sigmoidf_(acc[6] + b_xyz[0]) - 0.5f) * 0.05f;
    float o1 = (sigmoidf_(acc[7] + b_xyz[1]) - 0.5f) * 0.05f;
    float o2 = (sigmoidf_(acc[8] + b_xyz[2]) - 0.5f) * 0.05f;
    float opac = sigmoidf_(acc[9] + b_opac[0]);
    float qw = acc[10] + b_rot[0];
    float qx = acc[11] + b_rot[1];
    float qy = acc[12] + b_rot[2];
    float qz = acc[13] + b_rot[3];
    float qn = sqrtf(qw * qw + qx * qx + qy * qy + qz * qz);
    qw /= qn; qx /= qn; qy /= qn; qz /= qn;

    float R[3][3];
    R[0][0] = 1.f - 2.f * (qy * qy + qz * qz);
    R[0][1] = 2.f * (qx * qy - qw * qz);
    R[0][2] = 2.f * (qx * qz + qw * qy);
    R[1][0] = 2.f * (qx * qy + qw * qz);
    R[1][1] = 1.f - 2.f * (qx * qx + qz * qz);
    R[1][2] = 2.f * (qy * qz - qw * qx);
    R[2][0] = 2.f * (qx * qz - qw * qy);
    R[2][1] = 2.f * (qy * qz + qw * qx);
    R[2][2] = 1.f - 2.f * (qx * qx + qy * qy);

    float sq[3] = { s0 * s0, s1 * s1, s2 * s2 };
    float cov[3][3];
#pragma unroll
    for (int i = 0; i < 3; i++)
#pragma unroll
        for (int k = 0; k < 3; k++)
            cov[i][k] = R[i][0] * sq[0] * R[k][0] + R[i][1] * sq[1] * R[k][1] + R[i][2] * sq[2] * R[k][2];

    float Rv[3][3], tv[3];
#pragma unroll
    for (int i = 0; i < 3; i++) {
#pragma unroll
        for (int j = 0; j < 3; j++) Rv[i][j] = vm[i * 4 + j];
        tv[i] = vm[i * 4 + 3];
    }
    float X0 = pts[g * 3 + 0] + o0;
    float X1 = pts[g * 3 + 1] + o1;
    float X2 = pts[g * 3 + 2] + o2;
    float p0 = Rv[0][0] * X0 + Rv[0][1] * X1 + Rv[0][2] * X2 + tv[0];
    float p1 = Rv[1][0] * X0 + Rv[1][1] * X1 + Rv[1][2] * X2 + tv[1];
    float p2 = Rv[2][0] * X0 + Rv[2][1] * X1 + Rv[2][2] * X2 + tv[2];
    float tz = fmaxf(p2, 0.001f);
    float u = 128.0f * p0 / tz + 64.0f;
    float v = 128.0f * p1 / tz + 64.0f;

    float j00 = 128.0f / tz, j02 = -128.0f * p0 / (tz * tz);
    float j11 = 128.0f / tz, j12 = -128.0f * p1 / (tz * tz);
    float M0[3], M1[3];
#pragma unroll
    for (int k = 0; k < 3; k++) {
        M0[k] = j00 * Rv[0][k] + j02 * Rv[2][k];
        M1[k] = j11 * Rv[1][k] + j12 * Rv[2][k];
    }
    float t0[3], t1[3];
#pragma unroll
    for (int k = 0; k < 3; k++) {
        t0[k] = M0[0] * cov[0][k] + M0[1] * cov[1][k] + M0[2] * cov[2][k];
        t1[k] = M1[0] * cov[0][k] + M1[1] * cov[1][k] + M1[2] * cov[2][k];
    }
    float A = t0[0] * M0[0] + t0[1] * M0[1] + t0[2] * M0[2] + 0.3f;
    float B = t0[0] * M1[0] + t0[1] * M1[1] + t0[2] * M1[2];
    float C = t1[0] * M1[0] + t1[1] * M1[1] + t1[2] * M1[2] + 0.3f;
    float det = A * C - B * B + 1e-12f;
    float cA = C / det, cB = -B / det, cC = A / det;

    if (p2 <= 0.01f) opac = 0.0f;   // vis mask folded into opacity

    // conservative bounding half-extents for alpha >= 1/255
    float rx, ry;
    if (opac >= 1.0f / 255.0f) {
        float L = 2.0f * logf(255.0f * opac);
        rx = sqrtf(L * A) + 0.5f;
        ry = sqrtf(L * C) + 0.5f;
    } else {
        rx = -1e9f; ry = -1e9f;   // never kept
    }

    ws[P_U * NG + g]  = u;
    ws[P_V * NG + g]  = v;
    ws[P_A * NG + g]  = -0.5f * LOG2E * cA;
    ws[P_B * NG + g]  = -LOG2E * cB;
    ws[P_C * NG + g]  = -0.5f * LOG2E * cC;
    ws[P_OP * NG + g] = opac;
    ws[P_R * NG + g]  = r0;
    ws[P_G * NG + g]  = r1;
    ws[P_BL * NG + g] = r2;
    ws[P_RX * NG + g] = rx;
    ws[P_RY * NG + g] = ry;

    unsigned kb = __float_as_uint(tz);   // tz > 0 -> bits monotone in value
    ((unsigned long long*)(ws + KEY_OFF))[g] =
        ((unsigned long long)kb << 32) | (unsigned)g;
}

// rank sort: rank[g] = #{j : key_j < key_g}; keys distinct -> exact stable argsort.
// Then scatter all 11 params into depth-sorted arrays.
__global__ __launch_bounds__(64) void k_rank(float* __restrict__ ws)
{
    int g = blockIdx.x * 64 + threadIdx.x;
    const unsigned long long* __restrict__ key = (const unsigned long long*)(ws + KEY_OFF);
    unsigned long long mk = key[g];
    int rank = 0;
#pragma unroll 8
    for (int j = 0; j < NG; j++)
        rank += (key[j] < mk) ? 1 : 0;
#pragma unroll
    for (int a = 0; a < 11; a++)
        ws[SORT_OFF + a * NG + rank] = ws[a * NG + g];
}

// one block per 16x16 tile; walk all 8 chunks front-to-back with running T.
__global__ __launch_bounds__(256) void k_render(const float* __restrict__ ws, float* __restrict__ out)
{
    __shared__ float sg[CHSZ * 12];
    __shared__ int s_cnt[4];
    int tid = threadIdx.x;
    int tile = blockIdx.x;
    int tx0 = (tile & 7) << 4, ty0 = (tile >> 3) << 4;
    float x0 = tx0 + 0.5f, x1 = tx0 + 15.5f;
    float y0 = ty0 + 0.5f, y1 = ty0 + 15.5f;
    float gx = x0 + (float)(tid & 15);
    float gy = y0 + (float)(tid >> 4);
    const float* __restrict__ S = ws + SORT_OFF;
    int wid = tid >> 6, lane = tid & 63;

    float T = 1.0f, oR = 0.0f, oG = 0.0f, oB = 0.0f;
    for (int c = 0; c < NCHUNK; c++) {
        int s = c * CHSZ + tid;
        float u  = S[P_U * NG + s],  v  = S[P_V * NG + s];
        float rx = S[P_RX * NG + s], ry = S[P_RY * NG + s];
        bool keep = (u + rx >= x0) && (u - rx <= x1) && (v + ry >= y0) && (v - ry <= y1);

        unsigned long long mask = __ballot(keep);
        if (lane == 0) s_cnt[wid] = __popcll(mask);
        __syncthreads();
        int base = 0;
#pragma unroll
        for (int w2 = 0; w2 < 4; w2++) if (w2 < wid) base += s_cnt[w2];
        int n = s_cnt[0] + s_cnt[1] + s_cnt[2] + s_cnt[3];
        if (keep) {
            int pos = base + __popcll(mask & ((1ull << lane) - 1ull));
            float* d = &sg[pos * 12];
            d[0] = u;               d[1] = v;
            d[2] = S[P_A * NG + s]; d[3] = S[P_B * NG + s];
            d[4] = S[P_C * NG + s]; d[5] = S[P_OP * NG + s];
            d[6] = S[P_R * NG + s]; d[7] = S[P_G * NG + s];
            d[8] = S[P_BL * NG + s];
        }
        __syncthreads();

        for (int i = 0; i < n; i++) {
            const float* d = &sg[i * 12];
            float4 q0 = *(const float4*)d;        // u,v,a2,b2
            float4 q1 = *(const float4*)(d + 4);  // c2,op,r,g
            float bb = d[8];
            float dx = gx - q0.x;
            float dy = gy - q0.y;
            float pw = dx * (q0.z * dx + q0.w * dy) + q1.x * dy * dy;  // log2-scaled power
            pw = fminf(pw, 0.0f);
            float al = fminf(0.99f, q1.y * exp2f(pw));
            al = (al < 1.0f / 255.0f) ? 0.0f : al;
            float w = al * T;
            oR += w * q1.z;
            oG += w * q1.w;
            oB += w * bb;
            T -= al * T;
        }
    }
    int p = (ty0 + (tid >> 4)) * 128 + tx0 + (tid & 15);
    out[p * 3 + 0] = oR;
    out[p * 3 + 1] = oG;
    out[p * 3 + 2] = oB;
}

extern "C" void kernel_launch(void* const* d_in, const int* in_sizes, int n_in,
                              void* d_out, int out_size, void* d_ws, size_t ws_size,
                              hipStream_t stream)
{
    const float* x       = (const float*)d_in[0];
    const float* pts     = (const float*)d_in[1];
    const float* viewmat = (const float*)d_in[2];
    const float* w_shs   = (const float*)d_in[3];
    const float* b_shs   = (const float*)d_in[4];
    const float* w_scale = (const float*)d_in[5];
    const float* b_scale = (const float*)d_in[6];
    const float* w_xyz   = (const float*)d_in[7];
    const float* b_xyz   = (const float*)d_in[8];
    const float* w_opac  = (const float*)d_in[9];
    const float* b_opac  = (const float*)d_in[10];
    const float* w_rot   = (const float*)d_in[11];
    const float* b_rot   = (const float*)d_in[12];
    float* ws = (float*)d_ws;
    float* out = (float*)d_out;

    k_pre<<<NG / 64, 64, 0, stream>>>(x, pts, viewmat, w_shs, b_shs, w_scale, b_scale,
                                      w_xyz, b_xyz, w_opac, b_opac, w_rot, b_rot, ws);
    k_rank<<<NG / 64, 64, 0, stream>>>(ws);
    k_render<<<64, 256, 0, stream>>>(ws, out);
}

// Round 4
// 104.093 us; speedup vs baseline: 1.2357x; 1.2357x over previous
//
#include <hip/hip_runtime.h>
#include <math.h>

#define NG 2048
#define FEATN 128
#define NBLK 256
#define LOG2E 1.4426950408889634f

// ws layout, float4 indices:
//  RAW_A  f4[0    ..2048)  {u,v,rx,ry}
//  RAW_B  f4[2048 ..4096)  {a2,b2,c2,op}
//  RAW_C  f4[4096 ..6144)  {r,g,b,0}
//  KEY    u64 at float offset 24576 (byte 98304), 2048 entries
//  SORT_A f4[8192 ..10240)
//  SORT_B f4[10240..12288)
//  SORT_C f4[12288..14336)
//  BAR    byte offset 229376, 2 unsigned counters (memset to 0 each launch)
#define KEY_FOFF 24576
#define SORT_F4  8192
#define BAR_BYTE 229376

__device__ __forceinline__ float sigmoidf_(float z) { return 1.0f / (1.0f + expf(-z)); }

__device__ __forceinline__ void gbar(unsigned* c)
{
    __syncthreads();
    if (threadIdx.x == 0) {
        __threadfence();   // release all prior writes to device scope
        __hip_atomic_fetch_add(c, 1u, __ATOMIC_ACQ_REL, __HIP_MEMORY_SCOPE_AGENT);
        while (__hip_atomic_load(c, __ATOMIC_RELAXED, __HIP_MEMORY_SCOPE_AGENT) < NBLK)
            __builtin_amdgcn_s_sleep(2);
        __threadfence();   // acquire other blocks' writes
    }
    __syncthreads();
}

__global__ __launch_bounds__(64) void k_fused(
    const float* __restrict__ x, const float* __restrict__ pts, const float* __restrict__ vm,
    const float* __restrict__ w_shs, const float* __restrict__ b_shs,
    const float* __restrict__ w_scale, const float* __restrict__ b_scale,
    const float* __restrict__ w_xyz, const float* __restrict__ b_xyz,
    const float* __restrict__ w_opac, const float* __restrict__ b_opac,
    const float* __restrict__ w_rot, const float* __restrict__ b_rot,
    float* __restrict__ ws, float* __restrict__ out)
{
    __shared__ __attribute__((aligned(16))) unsigned char smem[16384];
    float* sw = (float*)smem;                            // phase A: 14*128 floats
    unsigned long long* skey = (unsigned long long*)smem; // phase B: 2048 u64
    float* comp = (float*)smem;                          // phase C: 64*12 floats

    const int tid = threadIdx.x;
    const int bid = blockIdx.x;
    float4* ws4 = (float4*)ws;
    unsigned long long* keyg = (unsigned long long*)(ws + KEY_FOFF);
    unsigned* bar = (unsigned*)((char*)ws + BAR_BYTE);

    // ================= phase A: per-gaussian params (blocks 0..31) =================
    if (bid < 32) {
        for (int i = tid; i < 14 * FEATN; i += 64) {
            int r = i >> 7, c0 = i & 127;
            float v;
            if (r < 3)       v = w_shs[r * FEATN + c0];
            else if (r < 6)  v = w_scale[(r - 3) * FEATN + c0];
            else if (r < 9)  v = w_xyz[(r - 6) * FEATN + c0];
            else if (r == 9) v = w_opac[c0];
            else             v = w_rot[(r - 10) * FEATN + c0];
            sw[i] = v;
        }
        __syncthreads();
        int g = bid * 64 + tid;

        float acc[14];
#pragma unroll
        for (int j = 0; j < 14; j++) acc[j] = 0.0f;
        const float4* x4 = (const float4*)(x + (size_t)g * FEATN);
#pragma unroll 4
        for (int k4 = 0; k4 < FEATN / 4; k4++) {
            float4 xv = x4[k4];
#pragma unroll
            for (int j = 0; j < 14; j++) {
                const float* wr = &sw[j * FEATN + k4 * 4];
                acc[j] += xv.x * wr[0] + xv.y * wr[1] + xv.z * wr[2] + xv.w * wr[3];
            }
        }

        float r0 = sigmoidf_(acc[0] + b_shs[0]);
        float r1 = sigmoidf_(acc[1] + b_shs[1]);
        float r2 = sigmoidf_(acc[2] + b_shs[2]);
        float s0 = fminf(expf(acc[3] + b_scale[0]), 0.2f);
        float s1 = fminf(expf(acc[4] + b_scale[1]), 0.2f);
        float s2 = fminf(expf(acc[5] + b_scale[2]), 0.2f);
        float o0 = (sigmoidf_(acc[6] + b_xyz[0]) - 0.5f) * 0.05f;
        float o1 = (sigmoidf_(acc[7] + b_xyz[1]) - 0.5f) * 0.05f;
        float o2 = (sigmoidf_(acc[8] + b_xyz[2]) - 0.5f) * 0.05f;
        float opac = sigmoidf_(acc[9] + b_opac[0]);
        float qw = acc[10] + b_rot[0];
        float qx = acc[11] + b_rot[1];
        float qy = acc[12] + b_rot[2];
        float qz = acc[13] + b_rot[3];
        float qn = sqrtf(qw * qw + qx * qx + qy * qy + qz * qz);
        qw /= qn; qx /= qn; qy /= qn; qz /= qn;

        float R[3][3];
        R[0][0] = 1.f - 2.f * (qy * qy + qz * qz);
        R[0][1] = 2.f * (qx * qy - qw * qz);
        R[0][2] = 2.f * (qx * qz + qw * qy);
        R[1][0] = 2.f * (qx * qy + qw * qz);
        R[1][1] = 1.f - 2.f * (qx * qx + qz * qz);
        R[1][2] = 2.f * (qy * qz - qw * qx);
        R[2][0] = 2.f * (qx * qz - qw * qy);
        R[2][1] = 2.f * (qy * qz + qw * qx);
        R[2][2] = 1.f - 2.f * (qx * qx + qy * qy);

        float sq[3] = { s0 * s0, s1 * s1, s2 * s2 };
        float cov[3][3];
#pragma unroll
        for (int i = 0; i < 3; i++)
#pragma unroll
            for (int k = 0; k < 3; k++)
                cov[i][k] = R[i][0] * sq[0] * R[k][0] + R[i][1] * sq[1] * R[k][1] + R[i][2] * sq[2] * R[k][2];

        float Rv[3][3], tv[3];
#pragma unroll
        for (int i = 0; i < 3; i++) {
#pragma unroll
            for (int j = 0; j < 3; j++) Rv[i][j] = vm[i * 4 + j];
            tv[i] = vm[i * 4 + 3];
        }
        float X0 = pts[g * 3 + 0] + o0;
        float X1 = pts[g * 3 + 1] + o1;
        float X2 = pts[g * 3 + 2] + o2;
        float p0 = Rv[0][0] * X0 + Rv[0][1] * X1 + Rv[0][2] * X2 + tv[0];
        float p1 = Rv[1][0] * X0 + Rv[1][1] * X1 + Rv[1][2] * X2 + tv[1];
        float p2 = Rv[2][0] * X0 + Rv[2][1] * X1 + Rv[2][2] * X2 + tv[2];
        float tz = fmaxf(p2, 0.001f);
        float u = 128.0f * p0 / tz + 64.0f;
        float v = 128.0f * p1 / tz + 64.0f;

        float j00 = 128.0f / tz, j02 = -128.0f * p0 / (tz * tz);
        float j11 = 128.0f / tz, j12 = -128.0f * p1 / (tz * tz);
        float M0[3], M1[3];
#pragma unroll
        for (int k = 0; k < 3; k++) {
            M0[k] = j00 * Rv[0][k] + j02 * Rv[2][k];
            M1[k] = j11 * Rv[1][k] + j12 * Rv[2][k];
        }
        float t0[3], t1[3];
#pragma unroll
        for (int k = 0; k < 3; k++) {
            t0[k] = M0[0] * cov[0][k] + M0[1] * cov[1][k] + M0[2] * cov[2][k];
            t1[k] = M1[0] * cov[0][k] + M1[1] * cov[1][k] + M1[2] * cov[2][k];
        }
        float A = t0[0] * M0[0] + t0[1] * M0[1] + t0[2] * M0[2] + 0.3f;
        float B = t0[0] * M1[0] + t0[1] * M1[1] + t0[2] * M1[2];
        float C = t1[0] * M1[0] + t1[1] * M1[1] + t1[2] * M1[2] + 0.3f;
        float det = A * C - B * B + 1e-12f;
        float cA = C / det, cB = -B / det, cC = A / det;

        if (p2 <= 0.01f) opac = 0.0f;   // vis mask folded into opacity

        float rx, ry;
        if (opac >= 1.0f / 255.0f) {
            float L = 2.0f * logf(255.0f * opac);
            rx = sqrtf(L * A) + 0.5f;
            ry = sqrtf(L * C) + 0.5f;
        } else {
            rx = -1e9f; ry = -1e9f;
        }

        ws4[0 * NG + g] = make_float4(u, v, rx, ry);
        ws4[1 * NG + g] = make_float4(-0.5f * LOG2E * cA, -LOG2E * cB, -0.5f * LOG2E * cC, opac);
        ws4[2 * NG + g] = make_float4(r0, r1, r2, 0.0f);
        unsigned kb = __float_as_uint(tz);
        keyg[g] = ((unsigned long long)kb << 32) | (unsigned)g;
    }
    gbar(&bar[0]);

    // ================= phase B: rank sort + scatter (all blocks, 8 g each) =========
    for (int i = tid; i < NG; i += 64) skey[i] = keyg[i];
    __syncthreads();
    {
        int gi = tid & 7, js = tid >> 3;
        int g = bid * 8 + gi;
        unsigned long long mk = skey[g];
        int base = js * 256, st = js * 37;
        int cnt = 0;
#pragma unroll 8
        for (int t = 0; t < 256; ++t) {
            int idx = base + ((t + st) & 255);
            cnt += (skey[idx] < mk) ? 1 : 0;
        }
        cnt += __shfl_xor(cnt, 8);
        cnt += __shfl_xor(cnt, 16);
        cnt += __shfl_xor(cnt, 32);
        if (js < 3)
            ws4[SORT_F4 + js * NG + cnt] = ws4[js * NG + g];
    }
    gbar(&bar[1]);

    // ================= phase C: render one 8x8 tile per block ======================
    const float4* SA = ws4 + SORT_F4;
    const float4* SB = ws4 + SORT_F4 + NG;
    const float4* SC = ws4 + SORT_F4 + 2 * NG;
    int lane = tid;
    int tx0 = (bid & 15) << 3, ty0 = (bid >> 4) << 3;
    float x0 = tx0 + 0.5f, x1 = tx0 + 7.5f;
    float y0 = ty0 + 0.5f, y1 = ty0 + 7.5f;
    float gx = x0 + (float)(lane & 7);
    float gy = y0 + (float)(lane >> 3);

    float T = 1.0f, oR = 0.0f, oG = 0.0f, oB = 0.0f;
    for (int r = 0; r < NG / 64; ++r) {
        int s = r * 64 + lane;
        float4 bb = SA[s];
        bool keep = (bb.x + bb.z >= x0) && (bb.x - bb.z <= x1) &&
                    (bb.y + bb.w >= y0) && (bb.y - bb.w <= y1);
        unsigned long long m = __ballot(keep);
        int n = __popcll(m);
        if (!n) continue;
        if (keep) {
            int pos = __popcll(m & ((1ull << lane) - 1ull));
            float4 q = SB[s];
            float4 cv = SC[s];
            float* e = comp + pos * 12;
            ((float4*)e)[0] = make_float4(bb.x, bb.y, q.x, q.y);   // u,v,a2,b2
            ((float4*)e)[1] = make_float4(q.z, q.w, cv.x, cv.y);   // c2,op,r,g
            e[8] = cv.z;                                           // b
        }
        __syncthreads();
        for (int i = 0; i < n; ++i) {
            const float* e = comp + i * 12;
            float4 e0 = ((const float4*)e)[0];
            float4 e1 = ((const float4*)e)[1];
            float bl = e[8];
            float dx = gx - e0.x, dy = gy - e0.y;
            float pw = dx * (e0.z * dx + e0.w * dy) + e1.x * dy * dy;  // log2-domain
            pw = fminf(pw, 0.0f);
            float al = fminf(0.99f, e1.y * exp2f(pw));
            al = (al < 1.0f / 255.0f) ? 0.0f : al;
            float w = al * T;
            oR += w * e1.z;
            oG += w * e1.w;
            oB += w * bl;
            T -= al * T;
        }
        __syncthreads();
        if (__ballot(T >= 1.5e-5f) == 0ull) break;   // all pixels saturated
    }
    int p = (ty0 + (lane >> 3)) * 128 + tx0 + (lane & 7);
    out[p * 3 + 0] = oR;
    out[p * 3 + 1] = oG;
    out[p * 3 + 2] = oB;
}

extern "C" void kernel_launch(void* const* d_in, const int* in_sizes, int n_in,
                              void* d_out, int out_size, void* d_ws, size_t ws_size,
                              hipStream_t stream)
{
    const float* x       = (const float*)d_in[0];
    const float* pts     = (const float*)d_in[1];
    const float* viewmat = (const float*)d_in[2];
    const float* w_shs   = (const float*)d_in[3];
    const float* b_shs   = (const float*)d_in[4];
    const float* w_scale = (const float*)d_in[5];
    const float* b_scale = (const float*)d_in[6];
    const float* w_xyz   = (const float*)d_in[7];
    const float* b_xyz   = (const float*)d_in[8];
    const float* w_opac  = (const float*)d_in[9];
    const float* b_opac  = (const float*)d_in[10];
    const float* w_rot   = (const float*)d_in[11];
    const float* b_rot   = (const float*)d_in[12];
    float* ws = (float*)d_ws;
    float* out = (float*)d_out;

    // zero the two grid-barrier counters (ws is NOT re-poisoned between replays,
    // so this must be part of the captured graph)
    hipMemsetAsync((char*)d_ws + BAR_BYTE, 0, 64, stream);

    k_fused<<<NBLK, 64, 0, stream>>>(x, pts, viewmat, w_shs, b_shs, w_scale, b_scale,
                                     w_xyz, b_xyz, w_opac, b_opac, w_rot, b_rot, ws, out);
}

// Round 5
// 76.007 us; speedup vs baseline: 1.6923x; 1.3695x over previous
//
#include <hip/hip_runtime.h>
#include <math.h>

#define NG 2048
#define FEATN 128
#define NBLK 256
#define LOG2E 1.4426950408889634f

typedef unsigned long long u64;

// ws layout, float4 indices:
//  RAW_A  f4[0    ..2048)  {u,v,rx,ry}
//  RAW_B  f4[2048 ..4096)  {a2,b2,c2,op}
//  RAW_C  f4[4096 ..6144)  {r,g,b,0}
//  KEY    u64 at float offset 24576, 2048 entries
//  SORT_A f4[8192 ..10240)
//  SORT_B f4[10240..12288)
//  SORT_C f4[12288..14336)
//  BAR    byte offset 229376, 2 u32 counters (memset to 0 each launch)
#define KEY_FOFF 24576
#define SORT_F4  8192
#define BAR_BYTE 229376

__device__ __forceinline__ float sigmoidf_(float z) { return 1.0f / (1.0f + expf(-z)); }

// ---- cross-XCD coherent (L1/L2-bypassing) data path: relaxed agent atomics ----
__device__ __forceinline__ void stg8(void* p, u64 v) {
    __hip_atomic_store((u64*)p, v, __ATOMIC_RELAXED, __HIP_MEMORY_SCOPE_AGENT);
}
__device__ __forceinline__ u64 ldg8(const void* p) {
    return __hip_atomic_load((const u64*)p, __ATOMIC_RELAXED, __HIP_MEMORY_SCOPE_AGENT);
}
__device__ __forceinline__ void st_f4(float4* p, float4 v) {
    union { float2 f; u64 u; } a, b;
    a.f = make_float2(v.x, v.y); b.f = make_float2(v.z, v.w);
    stg8(p, a.u); stg8((char*)p + 8, b.u);
}
__device__ __forceinline__ float4 ld_f4(const float4* p) {
    union { u64 u; float2 f; } a, b;
    a.u = ldg8(p); b.u = ldg8((const char*)p + 8);
    return make_float4(a.f.x, a.f.y, b.f.x, b.f.y);
}

// fence-free grid barrier: drain wave's sc1 stores, relaxed add, relaxed poll.
__device__ __forceinline__ void gbar(unsigned* c, unsigned target, bool contribute)
{
    __syncthreads();
    if (threadIdx.x == 0) {
        if (contribute) {
            asm volatile("s_waitcnt vmcnt(0)" ::: "memory");  // stores -> LLC
            __hip_atomic_fetch_add(c, 1u, __ATOMIC_RELAXED, __HIP_MEMORY_SCOPE_AGENT);
        }
        while (__hip_atomic_load(c, __ATOMIC_RELAXED, __HIP_MEMORY_SCOPE_AGENT) < target)
            __builtin_amdgcn_s_sleep(8);
    }
    __syncthreads();
}

__global__ __launch_bounds__(64) void k_fused(
    const float* __restrict__ x, const float* __restrict__ pts, const float* __restrict__ vm,
    const float* __restrict__ w_shs, const float* __restrict__ b_shs,
    const float* __restrict__ w_scale, const float* __restrict__ b_scale,
    const float* __restrict__ w_xyz, const float* __restrict__ b_xyz,
    const float* __restrict__ w_opac, const float* __restrict__ b_opac,
    const float* __restrict__ w_rot, const float* __restrict__ b_rot,
    float* __restrict__ ws, float* __restrict__ out)
{
    __shared__ __attribute__((aligned(16))) unsigned char smem[16384];
    float* sw = (float*)smem;            // phase A: 14*128 floats
    u64* skey = (u64*)smem;              // phase B: 2048 u64
    float* comp = (float*)smem;          // phase C: 64*12 floats

    const int tid = threadIdx.x;
    const int bid = blockIdx.x;
    float4* ws4 = (float4*)ws;
    u64* keyg = (u64*)(ws + KEY_FOFF);
    unsigned* bar = (unsigned*)((char*)ws + BAR_BYTE);

    // ================= phase A: per-gaussian params (blocks 0..31) =================
    if (bid < 32) {
        for (int i = tid; i < 14 * FEATN; i += 64) {
            int r = i >> 7, c0 = i & 127;
            float v;
            if (r < 3)       v = w_shs[r * FEATN + c0];
            else if (r < 6)  v = w_scale[(r - 3) * FEATN + c0];
            else if (r < 9)  v = w_xyz[(r - 6) * FEATN + c0];
            else if (r == 9) v = w_opac[c0];
            else             v = w_rot[(r - 10) * FEATN + c0];
            sw[i] = v;
        }
        __syncthreads();
        int g = bid * 64 + tid;

        float acc[14];
#pragma unroll
        for (int j = 0; j < 14; j++) acc[j] = 0.0f;
        const float4* x4 = (const float4*)(x + (size_t)g * FEATN);
#pragma unroll 4
        for (int k4 = 0; k4 < FEATN / 4; k4++) {
            float4 xv = x4[k4];
#pragma unroll
            for (int j = 0; j < 14; j++) {
                const float* wr = &sw[j * FEATN + k4 * 4];
                acc[j] += xv.x * wr[0] + xv.y * wr[1] + xv.z * wr[2] + xv.w * wr[3];
            }
        }

        float r0 = sigmoidf_(acc[0] + b_shs[0]);
        float r1 = sigmoidf_(acc[1] + b_shs[1]);
        float r2 = sigmoidf_(acc[2] + b_shs[2]);
        float s0 = fminf(expf(acc[3] + b_scale[0]), 0.2f);
        float s1 = fminf(expf(acc[4] + b_scale[1]), 0.2f);
        float s2 = fminf(expf(acc[5] + b_scale[2]), 0.2f);
        float o0 = (sigmoidf_(acc[6] + b_xyz[0]) - 0.5f) * 0.05f;
        float o1 = (sigmoidf_(acc[7] + b_xyz[1]) - 0.5f) * 0.05f;
        float o2 = (sigmoidf_(acc[8] + b_xyz[2]) - 0.5f) * 0.05f;
        float opac = sigmoidf_(acc[9] + b_opac[0]);
        float qw = acc[10] + b_rot[0];
        float qx = acc[11] + b_rot[1];
        float qy = acc[12] + b_rot[2];
        float qz = acc[13] + b_rot[3];
        float qn = sqrtf(qw * qw + qx * qx + qy * qy + qz * qz);
        qw /= qn; qx /= qn; qy /= qn; qz /= qn;

        float R[3][3];
        R[0][0] = 1.f - 2.f * (qy * qy + qz * qz);
        R[0][1] = 2.f * (qx * qy - qw * qz);
        R[0][2] = 2.f * (qx * qz + qw * qy);
        R[1][0] = 2.f * (qx * qy + qw * qz);
        R[1][1] = 1.f - 2.f * (qx * qx + qz * qz);
        R[1][2] = 2.f * (qy * qz - qw * qx);
        R[2][0] = 2.f * (qx * qz - qw * qy);
        R[2][1] = 2.f * (qy * qz + qw * qx);
        R[2][2] = 1.f - 2.f * (qx * qx + qy * qy);

        float sq[3] = { s0 * s0, s1 * s1, s2 * s2 };
        float cov[3][3];
#pragma unroll
        for (int i = 0; i < 3; i++)
#pragma unroll
            for (int k = 0; k < 3; k++)
                cov[i][k] = R[i][0] * sq[0] * R[k][0] + R[i][1] * sq[1] * R[k][1] + R[i][2] * sq[2] * R[k][2];

        float Rv[3][3], tv[3];
#pragma unroll
        for (int i = 0; i < 3; i++) {
#pragma unroll
            for (int j = 0; j < 3; j++) Rv[i][j] = vm[i * 4 + j];
            tv[i] = vm[i * 4 + 3];
        }
        float X0 = pts[g * 3 + 0] + o0;
        float X1 = pts[g * 3 + 1] + o1;
        float X2 = pts[g * 3 + 2] + o2;
        float p0 = Rv[0][0] * X0 + Rv[0][1] * X1 + Rv[0][2] * X2 + tv[0];
        float p1 = Rv[1][0] * X0 + Rv[1][1] * X1 + Rv[1][2] * X2 + tv[1];
        float p2 = Rv[2][0] * X0 + Rv[2][1] * X1 + Rv[2][2] * X2 + tv[2];
        float tz = fmaxf(p2, 0.001f);
        float u = 128.0f * p0 / tz + 64.0f;
        float v = 128.0f * p1 / tz + 64.0f;

        float j00 = 128.0f / tz, j02 = -128.0f * p0 / (tz * tz);
        float j11 = 128.0f / tz, j12 = -128.0f * p1 / (tz * tz);
        float M0[3], M1[3];
#pragma unroll
        for (int k = 0; k < 3; k++) {
            M0[k] = j00 * Rv[0][k] + j02 * Rv[2][k];
            M1[k] = j11 * Rv[1][k] + j12 * Rv[2][k];
        }
        float t0[3], t1[3];
#pragma unroll
        for (int k = 0; k < 3; k++) {
            t0[k] = M0[0] * cov[0][k] + M0[1] * cov[1][k] + M0[2] * cov[2][k];
            t1[k] = M1[0] * cov[0][k] + M1[1] * cov[1][k] + M1[2] * cov[2][k];
        }
        float A = t0[0] * M0[0] + t0[1] * M0[1] + t0[2] * M0[2] + 0.3f;
        float B = t0[0] * M1[0] + t0[1] * M1[1] + t0[2] * M1[2];
        float C = t1[0] * M1[0] + t1[1] * M1[1] + t1[2] * M1[2] + 0.3f;
        float det = A * C - B * B + 1e-12f;
        float cA = C / det, cB = -B / det, cC = A / det;

        if (p2 <= 0.01f) opac = 0.0f;   // vis mask folded into opacity

        float rx, ry;
        if (opac >= 1.0f / 255.0f) {
            float L = 2.0f * logf(255.0f * opac);
            rx = sqrtf(L * A) + 0.5f;
            ry = sqrtf(L * C) + 0.5f;
        } else {
            rx = -1e9f; ry = -1e9f;
        }

        st_f4(&ws4[0 * NG + g], make_float4(u, v, rx, ry));
        st_f4(&ws4[1 * NG + g], make_float4(-0.5f * LOG2E * cA, -LOG2E * cB, -0.5f * LOG2E * cC, opac));
        st_f4(&ws4[2 * NG + g], make_float4(r0, r1, r2, 0.0f));
        unsigned kb = __float_as_uint(tz);
        stg8(&keyg[g], ((u64)kb << 32) | (unsigned)g);
    }
    gbar(&bar[0], 32, bid < 32);

    // ================= phase B: rank sort + scatter (all blocks, 8 g each) =========
    for (int i = tid; i < NG; i += 64) skey[i] = ldg8(&keyg[i]);
    __syncthreads();
    {
        int gi = tid & 7, js = tid >> 3;
        int g = bid * 8 + gi;
        u64 mk = skey[g];
        int base = js * 256, st = js * 37;
        int cnt = 0;
#pragma unroll 8
        for (int t = 0; t < 256; ++t) {
            int idx = base + ((t + st) & 255);
            cnt += (skey[idx] < mk) ? 1 : 0;
        }
        cnt += __shfl_xor(cnt, 8);
        cnt += __shfl_xor(cnt, 16);
        cnt += __shfl_xor(cnt, 32);
        if (js < 3)
            st_f4(&ws4[SORT_F4 + js * NG + cnt], ld_f4(&ws4[js * NG + g]));
    }
    gbar(&bar[1], NBLK, true);

    // ================= phase C: render one 8x8 tile per block ======================
    const float4* SA = ws4 + SORT_F4;
    const float4* SB = ws4 + SORT_F4 + NG;
    const float4* SC = ws4 + SORT_F4 + 2 * NG;
    int lane = tid;
    int tx0 = (bid & 15) << 3, ty0 = (bid >> 4) << 3;
    float x0 = tx0 + 0.5f, x1 = tx0 + 7.5f;
    float y0 = ty0 + 0.5f, y1 = ty0 + 7.5f;
    float gx = x0 + (float)(lane & 7);
    float gy = y0 + (float)(lane >> 3);

    float T = 1.0f, oR = 0.0f, oG = 0.0f, oB = 0.0f;
    float4 nA = ld_f4(&SA[lane]);
    float4 nB = ld_f4(&SB[lane]);
    float4 nC = ld_f4(&SC[lane]);
    for (int r = 0; r < NG / 64; ++r) {
        float4 a = nA, b = nB, cv = nC;
        if (r + 1 < NG / 64) {               // prefetch next round (hides LLC latency)
            int s = (r + 1) * 64 + lane;
            nA = ld_f4(&SA[s]); nB = ld_f4(&SB[s]); nC = ld_f4(&SC[s]);
        }
        bool keep = (a.x + a.z >= x0) && (a.x - a.z <= x1) &&
                    (a.y + a.w >= y0) && (a.y - a.w <= y1);
        unsigned long long m = __ballot(keep);
        int n = __popcll(m);
        if (n) {
            if (keep) {
                int pos = __popcll(m & ((1ull << lane) - 1ull));
                float* e = comp + pos * 12;
                ((float4*)e)[0] = make_float4(a.x, a.y, b.x, b.y);   // u,v,a2,b2
                ((float4*)e)[1] = make_float4(b.z, b.w, cv.x, cv.y); // c2,op,r,g
                e[8] = cv.z;                                         // b
            }
            __syncthreads();
            for (int i = 0; i < n; ++i) {
                const float* e = comp + i * 12;
                float4 e0 = ((const float4*)e)[0];
                float4 e1 = ((const float4*)e)[1];
                float bl = e[8];
                float dx = gx - e0.x, dy = gy - e0.y;
                float pw = dx * (e0.z * dx + e0.w * dy) + e1.x * dy * dy;  // log2-domain
                pw = fminf(pw, 0.0f);
                float al = fminf(0.99f, e1.y * exp2f(pw));
                al = (al < 1.0f / 255.0f) ? 0.0f : al;
                float w = al * T;
                oR += w * e1.z;
                oG += w * e1.w;
                oB += w * bl;
                T -= al * T;
            }
            __syncthreads();
            if (__ballot(T >= 1.5e-5f) == 0ull) break;   // all pixels saturated
        }
    }
    int p = (ty0 + (lane >> 3)) * 128 + tx0 + (lane & 7);
    out[p * 3 + 0] = oR;
    out[p * 3 + 1] = oG;
    out[p * 3 + 2] = oB;
}

extern "C" void kernel_launch(void* const* d_in, const int* in_sizes, int n_in,
                              void* d_out, int out_size, void* d_ws, size_t ws_size,
                              hipStream_t stream)
{
    const float* x       = (const float*)d_in[0];
    const float* pts     = (const float*)d_in[1];
    const float* viewmat = (const float*)d_in[2];
    const float* w_shs   = (const float*)d_in[3];
    const float* b_shs   = (const float*)d_in[4];
    const float* w_scale = (const float*)d_in[5];
    const float* b_scale = (const float*)d_in[6];
    const float* w_xyz   = (const float*)d_in[7];
    const float* b_xyz   = (const float*)d_in[8];
    const float* w_opac  = (const float*)d_in[9];
    const float* b_opac  = (const float*)d_in[10];
    const float* w_rot   = (const float*)d_in[11];
    const float* b_rot   = (const float*)d_in[12];
    float* ws = (float*)d_ws;
    float* out = (float*)d_out;

    // zero the two grid-barrier counters (part of the captured graph; ws is not
    // re-poisoned between replays)
    hipMemsetAsync((char*)d_ws + BAR_BYTE, 0, 64, stream);

    k_fused<<<NBLK, 64, 0, stream>>>(x, pts, viewmat, w_shs, b_shs, w_scale, b_scale,
                                     w_xyz, b_xyz, w_opac, b_opac, w_rot, b_rot, ws, out);
}